// Round 8
// baseline (27.158 us; speedup 1.0000x reference)
//
#include <hip/hip_runtime.h>
#include <math.h>

// ---- constants ----
#define SLf   0.22360679774997896f   // sqrt(L), L = 0.05

// ---- table geometry ----
#define NTAB   1024
#define XMINf  -17.0f
#define DXf    (23.0f / 1023.0f)
#define INVDXf (1023.0f / 23.0f)

__device__ float4 tab4[NTAB];      // .x = g, .y = G, .z = H

// ================= f64 g (only for C0) =================
__device__ double g_dbl(double x) {
    if (x >= -3.0) return 0.8862269254527580 * exp(x * x) * (1.0 + erf(x));
    double z = -x, iz2 = 1.0 / (z * z);
    return (0.5 / z) * (1.0 + iz2 * (-0.5 + iz2 * (0.75 - 1.875 * iz2)));
}

// ================= f32 g: erfc-based, cancellation-free =================
__device__ __forceinline__ float g_f32(float x) {
    if (x >= -3.0f) {
        // sqrt(pi)/2 * e^{x^2} * (1+erf(x)) = C * e^{x^2} * erfc(-x)
        return 0.88622692545275801f * __expf(x * x) * erfcf(-x);
    }
    float z = -x, iz = 1.0f / z, iz2 = iz * iz;
    return 0.5f * iz * (1.0f + iz2 * (-0.5f + iz2 * (0.75f - 1.875f * iz2)));
}

// ========== GL node solve: 2 sweeps total ==========
// sweep 1: one Newton update from Tricomi guess (err 1e-4 -> ~1e-9)
// sweep 2: evaluate P,P' at z1; final update z2 = z1 - P/P' (err ~1e-16);
//          weight from P'(z1) — rel err ~4z/(1-z^2)*1e-9 < 2e-6, below f32.
template <int N>
__device__ void gl_node_t(int i, const double* __restrict__ inv, double* x01, double* w01) {
    double z = cos(3.14159265358979323846 * ((double)i + 0.75) / ((double)N + 0.5));
    double pl, pm, pp;
    // sweep 1
    pm = 1.0; pl = z;
    #pragma unroll
    for (int k = 2; k <= N; ++k) {
        double pk = ((2.0 * k - 1.0) * z * pl - (k - 1.0) * pm) * inv[k];
        pm = pl; pl = pk;
    }
    pp = (double)N * (z * pl - pm) / (z * z - 1.0);
    z -= pl / pp;
    // sweep 2
    pm = 1.0; pl = z;
    #pragma unroll
    for (int k = 2; k <= N; ++k) {
        double pk = ((2.0 * k - 1.0) * z * pl - (k - 1.0) * pm) * inv[k];
        pm = pl; pl = pk;
    }
    pp = (double)N * (z * pl - pm) / (z * z - 1.0);
    double z2 = z - pl / pp;
    *x01 = 0.5 * (z2 + 1.0);
    *w01 = 1.0 / ((1.0 - z2 * z2) * pp * pp);   // weight mapped to [0,1]
}

// ============ single init kernel: GL nodes (redundant per block) + tables =======
// 256 blocks x 128 threads (2 waves); block b builds entries [4b, 4b+4), 32 lanes each.
// Wave 0 lanes 0-47: GL-48 Newton.  Wave 1 lanes 0-31 (tid 64-95): GL-32 Newton + C0.
__global__ __launch_bounds__(128) void build_tables() {
    __shared__ double s_inv[65];
    __shared__ float sA48[48], sW48[48];
    __shared__ float sA32[32], sW32[32], sR32[32], sWQ[32];
    __shared__ float sC0;
    int tid = threadIdx.x;
    if (tid >= 2 && tid <= 64) s_inv[tid] = 1.0 / (double)tid;
    __syncthreads();

    if (tid < 48) {                              // wave 0: GL-48
        double x, w; gl_node_t<48>(tid, s_inv, &x, &w);
        sA48[tid] = (float)x; sW48[tid] = (float)w;
    } else if (tid >= 64 && tid < 96) {          // wave 1: GL-32 (+derived +C0)
        int j = tid - 64;
        double x, w; gl_node_t<32>(j, s_inv, &x, &w);
        sA32[j] = (float)x; sW32[j] = (float)w;
        sR32[j] = (float)(-log1p(-x));
        sWQ[j]  = (float)(w / (1.0 - x));
        // C0 = int_{-inf}^0 e^{-s^2} g(s)^2 ds via the same 32-pt r-mapped rule
        double r = -log1p(-x);
        double gv = g_dbl(-r);
        double term = w * exp(-r * r) * gv * gv / (1.0 - x);
        #pragma unroll
        for (int off = 16; off > 0; off >>= 1)
            term += __shfl_down(term, off, 32);
        if (j == 0) sC0 = (float)term;
    }
    __syncthreads();

    int k = blockIdx.x * 4 + (tid >> 5);         // table entry
    int i = tid & 31;                            // lane within entry
    float x = XMINf + DXf * (float)k;

    // G partial: nodes i and i+32 (48 nodes over 32 lanes)
    float aG = sW48[i] * g_f32(x * sA48[i]);
    if (i < 16) aG = fmaf(sW48[i + 32], g_f32(x * sA48[i + 32]), aG);

    float Hp, aE = 0.0f;
    float t = x * sA32[i];
    if (x < 0.0f) {
        // H_neg partial: W_i * h(t), h via 32-pt r-mapped rule (ref _h_neg)
        float h = 0.0f;
        for (int j = 0; j < 32; ++j) {
            float r = sR32[j];
            float gg = g_f32(t - r);             // arg <= 0 always
            h = fmaf(sWQ[j], __expf((2.0f * t - r) * r) * gg * gg, h);
        }
        Hp = sW32[i] * h;
    } else {
        // H_pos partial: W_i a_i e^{t^2} * inner(t) (ref H_pos)
        float inner = 0.0f;
        for (int j = 0; j < 32; ++j) {
            float s = t * sA32[j];
            float gs = g_f32(s);
            inner = fmaf(sW32[j], __expf(-s * s) * gs * gs, inner);
        }
        Hp = sW32[i] * sA32[i] * __expf(t * t) * inner;
        // E partial (48 nodes over 32 lanes)
        float t0 = x * sA48[i];
        aE = sW48[i] * __expf(t0 * t0);
        if (i < 16) {
            float t1 = x * sA48[i + 32];
            aE = fmaf(sW48[i + 32], __expf(t1 * t1), aE);
        }
    }

    // butterfly reduce within each 32-lane entry group
    #pragma unroll
    for (int off = 16; off > 0; off >>= 1) {
        aG += __shfl_xor(aG, off, 32);
        Hp += __shfl_xor(Hp, off, 32);
        aE += __shfl_xor(aE, off, 32);
    }

    if (i == 0) {
        float Hv = (x < 0.0f) ? x * Hp
                              : sC0 * (x * aE) + x * x * Hp;
        float4 e; e.x = g_f32(x); e.y = x * aG; e.z = Hv; e.w = 0.0f;
        tab4[k] = e;
    }
}

// ================= main kernel: packed float4 cubic lookups, 2 elems/thread ======
__device__ __forceinline__ void cr_weights(float x, int* kk, float* w) {
    float u = (x - XMINf) * INVDXf;
    u = fminf(fmaxf(u, 1.0f), (float)(NTAB - 3));
    int k = (int)u;
    if (k > NTAB - 3) k = NTAB - 3;
    float f = u - (float)k;
    float f2 = f * f, f3 = f2 * f;
    w[0] = 0.5f * (-f + 2.0f * f2 - f3);
    w[1] = 1.0f + 0.5f * (-5.0f * f2 + 3.0f * f3);
    w[2] = 0.5f * (f + 4.0f * f2 - 3.0f * f3);
    w[3] = 0.5f * (f3 - f2);
    *kk = k;
}

__device__ __forceinline__ void mnn_one(float u, float s,
        float* ua_o, float* sa_o, float* chi_o) {
    float ua = 0.0f, sa = 0.0f, chi = 0.0f;
    bool sgt0 = (s > 0.0f);
    bool reg1 = sgt0 && ((1.0f - u) < 10.0f * SLf * s);   // VT*L = 1

    if (reg1) {
        float inv = 1.0f / (SLf * s);
        float ub = (1.0f - u) * inv;
        float lb = -u * inv;                    // always <= 0

        int ku, kl; float wu[4], wl[4];
        cr_weights(ub, &ku, wu);
        cr_weights(lb, &kl, wl);
        float4 a0 = tab4[ku - 1], a1 = tab4[ku], a2 = tab4[ku + 1], a3 = tab4[ku + 2];
        float4 b0 = tab4[kl - 1], b1 = tab4[kl], b2 = tab4[kl + 1], b3 = tab4[kl + 2];

        float g_ub = wu[0]*a0.x + wu[1]*a1.x + wu[2]*a2.x + wu[3]*a3.x;
        float G_ub = wu[0]*a0.y + wu[1]*a1.y + wu[2]*a2.y + wu[3]*a3.y;
        float H_ub = wu[0]*a0.z + wu[1]*a1.z + wu[2]*a2.z + wu[3]*a3.z;
        float g_lb = wl[0]*b0.x + wl[1]*b1.x + wl[2]*b2.x + wl[3]*b3.x;
        float G_lb = wl[0]*b0.y + wl[1]*b1.y + wl[2]*b2.y + wl[3]*b3.y;
        float H_lb = wl[0]*b0.z + wl[1]*b1.z + wl[2]*b2.z + wl[3]*b3.z;

        float dG = G_ub - G_lb;
        float ua1 = 1.0f / (40.0f * dG + 5.0f); // (2/L)*dG + TREF
        float dH = H_ub - H_lb;

        float fano = 3200.0f * dH * ua1 * ua1;  // 8/L^2
        float val = fano * ua1;
        float s_a = (val > 0.0f) ? sqrtf(val) : 0.0f;

        float dg = g_ub - g_lb;
        float sa_safe = (s_a > 0.0f) ? s_a : 1.0f;
        chi = ua1 * ua1 * dg * 178.88543819998318f / sa_safe;  // 2/L^1.5
        ua = ua1; sa = s_a;
    } else if (!sgt0 && u > 1.0f) {            // region 2
        float logt = 5.0f - 20.0f * logf(1.0f - 1.0f / u);
        ua = 1.0f / logt;
        chi = 6.324555320336759f / (sqrtf(logt) * sqrtf(2.0f * u - 1.0f)); // sqrt(40)
    }
    *ua_o = ua; *sa_o = sa; *chi_o = chi;
}

__global__ __launch_bounds__(256) void mnn_main(const float2* __restrict__ U2,
        const float2* __restrict__ S2, float* __restrict__ out, int n) {
    int idx = blockIdx.x * blockDim.x + threadIdx.x;   // pair index
    int npair = n >> 1;
    if (idx >= npair) return;
    float2 uu = U2[idx], ss = S2[idx];

    float2 ua, sa, chi;
    mnn_one(uu.x, ss.x, &ua.x, &sa.x, &chi.x);
    mnn_one(uu.y, ss.y, &ua.y, &sa.y, &chi.y);

    float2* o0 = (float2*)out;
    float2* o1 = (float2*)(out + n);
    float2* o2 = (float2*)(out + 2 * n);
    o0[idx] = ua;
    o1[idx] = sa;
    o2[idx] = chi;
}

// ================= launch =================
extern "C" void kernel_launch(void* const* d_in, const int* in_sizes, int n_in,
                              void* d_out, int out_size, void* d_ws, size_t ws_size,
                              hipStream_t stream) {
    const float* u = (const float*)d_in[0];
    const float* s = (const float*)d_in[1];
    float* out = (float*)d_out;
    int n = in_sizes[0];

    build_tables<<<dim3(NTAB / 4), dim3(128), 0, stream>>>();
    int npair = n >> 1;
    mnn_main<<<dim3((npair + 255) / 256), dim3(256), 0, stream>>>(
        (const float2*)u, (const float2*)s, out, n);
}

// Round 9
// 26.746 us; speedup vs baseline: 1.0154x; 1.0154x over previous
//
#include <hip/hip_runtime.h>
#include <math.h>

// ---- constants ----
#define SLf   0.22360679774997896f   // sqrt(L), L = 0.05

// ---- table geometry ----
#define NTAB   1024
#define XMINf  -17.0f
#define DXf    (23.0f / 1023.0f)
#define INVDXf (1023.0f / 23.0f)

__device__ float4 tab4[NTAB];      // .x = g, .y = G, .z = H

// ================= f64 g (only for C0) =================
__device__ double g_dbl(double x) {
    if (x >= -3.0) return 0.8862269254527580 * exp(x * x) * (1.0 + erf(x));
    double z = -x, iz2 = 1.0 / (z * z);
    return (0.5 / z) * (1.0 + iz2 * (-0.5 + iz2 * (0.75 - 1.875 * iz2)));
}

// ================= f32 g: erfc-based, cancellation-free =================
__device__ __forceinline__ float g_f32(float x) {
    if (x >= -3.0f) {
        // sqrt(pi)/2 * e^{x^2} * (1+erf(x)) = C * e^{x^2} * erfc(-x)
        return 0.88622692545275801f * __expf(x * x) * erfcf(-x);
    }
    float z = -x, iz = 1.0f / z, iz2 = iz * iz;
    return 0.5f * iz * (1.0f + iz2 * (-0.5f + iz2 * (0.75f - 1.875f * iz2)));
}

// ========== GL node solve: 2 sweeps total ==========
// sweep 1: one Newton update from Tricomi guess (err 1e-4 -> ~1e-9)
// sweep 2: evaluate P,P' at z1; final update z2 = z1 - P/P' (err ~1e-16);
//          weight from P'(z1) — rel err < 2e-6, below f32 table storage.
template <int N>
__device__ void gl_node_t(int i, const double* __restrict__ inv, double* x01, double* w01) {
    double z = cos(3.14159265358979323846 * ((double)i + 0.75) / ((double)N + 0.5));
    double pl, pm, pp;
    // sweep 1
    pm = 1.0; pl = z;
    #pragma unroll
    for (int k = 2; k <= N; ++k) {
        double pk = ((2.0 * k - 1.0) * z * pl - (k - 1.0) * pm) * inv[k];
        pm = pl; pl = pk;
    }
    pp = (double)N * (z * pl - pm) / (z * z - 1.0);
    z -= pl / pp;
    // sweep 2
    pm = 1.0; pl = z;
    #pragma unroll
    for (int k = 2; k <= N; ++k) {
        double pk = ((2.0 * k - 1.0) * z * pl - (k - 1.0) * pm) * inv[k];
        pm = pl; pl = pk;
    }
    pp = (double)N * (z * pl - pm) / (z * z - 1.0);
    double z2 = z - pl / pp;
    *x01 = 0.5 * (z2 + 1.0);
    *w01 = 1.0 / ((1.0 - z2 * z2) * pp * pp);   // weight mapped to [0,1]
}

// ============ single init kernel: GL nodes (redundant per block) + tables =======
// 256 blocks x 128 threads (2 waves); block b builds entries [4b, 4b+4), 32 lanes each.
// Wave 0 lanes 0-47: GL-48 Newton.  Wave 1 lanes 0-31 (tid 64-95): GL-32 Newton + C0.
__global__ __launch_bounds__(128) void build_tables() {
    __shared__ double s_inv[65];
    __shared__ float sA48[48], sW48[48];
    __shared__ float sA32[32], sW32[32], sR32[32], sWQ[32];
    __shared__ float sC0;
    int tid = threadIdx.x;
    if (tid >= 2 && tid <= 64) s_inv[tid] = 1.0 / (double)tid;
    __syncthreads();

    if (tid < 48) {                              // wave 0: GL-48
        double x, w; gl_node_t<48>(tid, s_inv, &x, &w);
        sA48[tid] = (float)x; sW48[tid] = (float)w;
    } else if (tid >= 64 && tid < 96) {          // wave 1: GL-32 (+derived +C0)
        int j = tid - 64;
        double x, w; gl_node_t<32>(j, s_inv, &x, &w);
        sA32[j] = (float)x; sW32[j] = (float)w;
        sR32[j] = (float)(-log1p(-x));
        sWQ[j]  = (float)(w / (1.0 - x));
        // C0 = int_{-inf}^0 e^{-s^2} g(s)^2 ds via the same 32-pt r-mapped rule
        double r = -log1p(-x);
        double gv = g_dbl(-r);
        double term = w * exp(-r * r) * gv * gv / (1.0 - x);
        #pragma unroll
        for (int off = 16; off > 0; off >>= 1)
            term += __shfl_down(term, off, 32);
        if (j == 0) sC0 = (float)term;
    }
    __syncthreads();

    int k = blockIdx.x * 4 + (tid >> 5);         // table entry
    int i = tid & 31;                            // lane within entry
    float x = XMINf + DXf * (float)k;

    // G partial: nodes i and i+32 (48 nodes over 32 lanes)
    float aG = sW48[i] * g_f32(x * sA48[i]);
    if (i < 16) aG = fmaf(sW48[i + 32], g_f32(x * sA48[i + 32]), aG);

    float Hp, aE = 0.0f;
    float t = x * sA32[i];
    if (x < 0.0f) {
        // H_neg partial: W_i * h(t), h via 32-pt r-mapped rule (ref _h_neg)
        float h = 0.0f;
        for (int j = 0; j < 32; ++j) {
            float r = sR32[j];
            float gg = g_f32(t - r);             // arg <= 0 always
            h = fmaf(sWQ[j], __expf((2.0f * t - r) * r) * gg * gg, h);
        }
        Hp = sW32[i] * h;
    } else {
        // H_pos partial: W_i a_i e^{t^2} * inner(t) (ref H_pos)
        float inner = 0.0f;
        for (int j = 0; j < 32; ++j) {
            float s = t * sA32[j];
            float gs = g_f32(s);
            inner = fmaf(sW32[j], __expf(-s * s) * gs * gs, inner);
        }
        Hp = sW32[i] * sA32[i] * __expf(t * t) * inner;
        // E partial (48 nodes over 32 lanes)
        float t0 = x * sA48[i];
        aE = sW48[i] * __expf(t0 * t0);
        if (i < 16) {
            float t1 = x * sA48[i + 32];
            aE = fmaf(sW48[i + 32], __expf(t1 * t1), aE);
        }
    }

    // butterfly reduce within each 32-lane entry group
    #pragma unroll
    for (int off = 16; off > 0; off >>= 1) {
        aG += __shfl_xor(aG, off, 32);
        Hp += __shfl_xor(Hp, off, 32);
        aE += __shfl_xor(aE, off, 32);
    }

    if (i == 0) {
        float Hv = (x < 0.0f) ? x * Hp
                              : sC0 * (x * aE) + x * x * Hp;
        float4 e; e.x = g_f32(x); e.y = x * aG; e.z = Hv; e.w = 0.0f;
        tab4[k] = e;
    }
}

// ================= main kernel: packed float4 cubic lookups (1 elem/thread) ======
__device__ __forceinline__ void cr_weights(float x, int* kk, float* w) {
    float u = (x - XMINf) * INVDXf;
    u = fminf(fmaxf(u, 1.0f), (float)(NTAB - 3));
    int k = (int)u;
    if (k > NTAB - 3) k = NTAB - 3;
    float f = u - (float)k;
    float f2 = f * f, f3 = f2 * f;
    w[0] = 0.5f * (-f + 2.0f * f2 - f3);
    w[1] = 1.0f + 0.5f * (-5.0f * f2 + 3.0f * f3);
    w[2] = 0.5f * (f + 4.0f * f2 - 3.0f * f3);
    w[3] = 0.5f * (f3 - f2);
    *kk = k;
}

__global__ __launch_bounds__(256) void mnn_main(const float* __restrict__ U,
        const float* __restrict__ S, float* __restrict__ out, int n) {
    int idx = blockIdx.x * blockDim.x + threadIdx.x;
    if (idx >= n) return;
    float u = U[idx], s = S[idx];
    float ua = 0.0f, sa = 0.0f, chi = 0.0f;

    bool sgt0 = (s > 0.0f);
    bool reg1 = sgt0 && ((1.0f - u) < 10.0f * SLf * s);   // VT*L = 1

    if (reg1) {
        float inv = 1.0f / (SLf * s);
        float ub = (1.0f - u) * inv;
        float lb = -u * inv;                    // always <= 0

        int ku, kl; float wu[4], wl[4];
        cr_weights(ub, &ku, wu);
        cr_weights(lb, &kl, wl);
        float4 a0 = tab4[ku - 1], a1 = tab4[ku], a2 = tab4[ku + 1], a3 = tab4[ku + 2];
        float4 b0 = tab4[kl - 1], b1 = tab4[kl], b2 = tab4[kl + 1], b3 = tab4[kl + 2];

        float g_ub = wu[0]*a0.x + wu[1]*a1.x + wu[2]*a2.x + wu[3]*a3.x;
        float G_ub = wu[0]*a0.y + wu[1]*a1.y + wu[2]*a2.y + wu[3]*a3.y;
        float H_ub = wu[0]*a0.z + wu[1]*a1.z + wu[2]*a2.z + wu[3]*a3.z;
        float g_lb = wl[0]*b0.x + wl[1]*b1.x + wl[2]*b2.x + wl[3]*b3.x;
        float G_lb = wl[0]*b0.y + wl[1]*b1.y + wl[2]*b2.y + wl[3]*b3.y;
        float H_lb = wl[0]*b0.z + wl[1]*b1.z + wl[2]*b2.z + wl[3]*b3.z;

        float dG = G_ub - G_lb;
        float ua1 = 1.0f / (40.0f * dG + 5.0f); // (2/L)*dG + TREF
        float dH = H_ub - H_lb;

        float fano = 3200.0f * dH * ua1 * ua1;  // 8/L^2
        float val = fano * ua1;
        float s_a = (val > 0.0f) ? sqrtf(val) : 0.0f;

        float dg = g_ub - g_lb;
        float sa_safe = (s_a > 0.0f) ? s_a : 1.0f;
        chi = ua1 * ua1 * dg * 178.88543819998318f / sa_safe;  // 2/L^1.5
        ua = ua1; sa = s_a;
    } else if (!sgt0 && u > 1.0f) {            // region 2
        float logt = 5.0f - 20.0f * logf(1.0f - 1.0f / u);
        ua = 1.0f / logt;
        chi = 6.324555320336759f / (sqrtf(logt) * sqrtf(2.0f * u - 1.0f)); // sqrt(40)
    }

    out[idx] = ua;
    out[n + idx] = sa;
    out[2 * n + idx] = chi;
}

// ================= launch =================
extern "C" void kernel_launch(void* const* d_in, const int* in_sizes, int n_in,
                              void* d_out, int out_size, void* d_ws, size_t ws_size,
                              hipStream_t stream) {
    const float* u = (const float*)d_in[0];
    const float* s = (const float*)d_in[1];
    float* out = (float*)d_out;
    int n = in_sizes[0];

    build_tables<<<dim3(NTAB / 4), dim3(128), 0, stream>>>();
    mnn_main<<<dim3((n + 255) / 256), dim3(256), 0, stream>>>(u, s, out, n);
}